// Round 1
// baseline (315.423 us; speedup 1.0000x reference)
//
#include <hip/hip_runtime.h>
#include <hip/hip_bf16.h>
#include <stdint.h>

typedef __attribute__((ext_vector_type(8))) __bf16 bf16x8;
typedef __attribute__((ext_vector_type(4))) __bf16 bf16x4;
typedef __attribute__((ext_vector_type(4))) float f32x4;

#define DEV __device__ __forceinline__

static constexpr int S = 2048, F = 2048, H = 16, D = 128;
static constexpr int KDIM = F;            // 2048
static constexpr float QSCALE = 0.08838834764831845f;  // 1/sqrt(128)

DEV void gll16(const void* g, void* l) {
  __builtin_amdgcn_global_load_lds(
      (const __attribute__((address_space(1))) void*)g,
      (__attribute__((address_space(3))) void*)l, 16, 0, 0);
}

DEV f32x4 mfma16(bf16x8 a, bf16x8 b, f32x4 c) {
  return __builtin_amdgcn_mfma_f32_16x16x32_bf16(a, b, c, 0, 0, 0);
}

// ---------------- elementwise f32 -> bf16 ----------------
__global__ void k_cvt(const float* __restrict__ in, __bf16* __restrict__ out) {
  int i = blockIdx.x * 256 + threadIdx.x;
  float4 v = reinterpret_cast<const float4*>(in)[i];
  bf16x4 o = {(__bf16)v.x, (__bf16)v.y, (__bf16)v.z, (__bf16)v.w};
  reinterpret_cast<bf16x4*>(out)[i] = o;
}

// ---------------- transpose f32 [rows][cols] -> bf16 [cols][rows] ----------------
__global__ void k_transpose(const float* __restrict__ in, __bf16* __restrict__ out,
                            int rows, int cols) {
  __shared__ float t[64][65];
  const int c0 = blockIdx.x * 64, r0 = blockIdx.y * 64;
  const int tx = threadIdx.x & 63, ty = threadIdx.x >> 6;
#pragma unroll
  for (int i = 0; i < 64; i += 4)
    t[ty + i][tx] = in[(size_t)(r0 + ty + i) * cols + c0 + tx];
  __syncthreads();
#pragma unroll
  for (int i = 0; i < 64; i += 4)
    out[(size_t)(c0 + ty + i) * rows + r0 + tx] = (__bf16)t[tx][ty + i];
}

// ---------------- GEMM: C[M,N] = A[M,K] * Bt[N,K]^T (+bias) ----------------
// 128x128 tile, BK=32, 256 thr (4 waves 2x2). EPI 0: route QKV bf16. EPI 1: f32 out.
template <int EPI>
__global__ __launch_bounds__(256, 2) void k_gemm(
    const __bf16* __restrict__ A, const __bf16* __restrict__ Bt,
    const float* __restrict__ bias,
    __bf16* __restrict__ qo, __bf16* __restrict__ ko, __bf16* __restrict__ vo,
    float* __restrict__ fo) {
  __shared__ __bf16 As[128 * 32];
  __shared__ __bf16 Bs[128 * 32];
  const int lane = threadIdx.x & 63, w = threadIdx.x >> 6;
  const int wm = w >> 1, wn = w & 1;
  const int lm = lane >> 4, ln = lane & 15;
  const int mBase = blockIdx.y * 128, nBase = blockIdx.x * 128;

  f32x4 acc[4][4] = {};

  for (int k0 = 0; k0 < KDIM; k0 += 32) {
    __syncthreads();
#pragma unroll
    for (int j = 0; j < 2; ++j) {
      // chunk cidx covers LDS bytes [cidx*16, +16); swizzle on global source (m173)
      int cidx = (w * 2 + j) * 64 + lane;
      int row = cidx >> 2;
      int ps = (cidx & 3) ^ ((row >> 1) & 3);
      gll16(A + (size_t)(mBase + row) * KDIM + k0 + ps * 8, (char*)As + (w * 2 + j) * 1024);
      gll16(Bt + (size_t)(nBase + row) * KDIM + k0 + ps * 8, (char*)Bs + (w * 2 + j) * 1024);
    }
    __syncthreads();
    bf16x8 af[4], bfr[4];
#pragma unroll
    for (int mi = 0; mi < 4; ++mi) {
      int row = wm * 64 + mi * 16 + ln;
      int q = lm ^ ((row >> 1) & 3);
      af[mi] = *reinterpret_cast<const bf16x8*>((const char*)As + row * 64 + q * 16);
    }
#pragma unroll
    for (int ni = 0; ni < 4; ++ni) {
      int row = wn * 64 + ni * 16 + ln;
      int q = lm ^ ((row >> 1) & 3);
      bfr[ni] = *reinterpret_cast<const bf16x8*>((const char*)Bs + row * 64 + q * 16);
    }
#pragma unroll
    for (int mi = 0; mi < 4; ++mi)
#pragma unroll
      for (int ni = 0; ni < 4; ++ni)
        acc[mi][ni] = mfma16(af[mi], bfr[ni], acc[mi][ni]);
  }

  if (EPI == 0) {
    // whole 128-col tile lies in one section (Q/K/V) and one head
    const int sec = nBase >> 11;
    const int h = (nBase & 2047) >> 7;
#pragma unroll
    for (int mi = 0; mi < 4; ++mi) {
      const int m0 = mBase + wm * 64 + mi * 16 + lm * 4;
      const int b = m0 >> 11;
      const int s0 = m0 & 2047;
      const int bh = b * H + h;
#pragma unroll
      for (int ni = 0; ni < 4; ++ni) {
        const int nG = nBase + wn * 64 + ni * 16 + ln;
        const float bv = bias[nG];
        const int d = nG & 127;
        if (sec == 0) {
#pragma unroll
          for (int r = 0; r < 4; ++r)
            qo[((size_t)bh * S + s0 + r) * D + d] = (__bf16)((acc[mi][ni][r] + bv) * QSCALE);
        } else if (sec == 1) {
#pragma unroll
          for (int r = 0; r < 4; ++r)
            ko[((size_t)bh * S + s0 + r) * D + d] = (__bf16)(acc[mi][ni][r] + bv);
        } else {
          bf16x4 pv = {(__bf16)(acc[mi][ni][0] + bv), (__bf16)(acc[mi][ni][1] + bv),
                       (__bf16)(acc[mi][ni][2] + bv), (__bf16)(acc[mi][ni][3] + bv)};
          *reinterpret_cast<bf16x4*>(vo + ((size_t)bh * D + d) * S + s0) = pv;  // V^T
        }
      }
    }
  } else {
#pragma unroll
    for (int mi = 0; mi < 4; ++mi) {
      const int m0 = mBase + wm * 64 + mi * 16 + lm * 4;
#pragma unroll
      for (int ni = 0; ni < 4; ++ni) {
        const int nG = nBase + wn * 64 + ni * 16 + ln;
        const float bv = bias[nG];
#pragma unroll
        for (int r = 0; r < 4; ++r)
          fo[(size_t)(m0 + r) * F + nG] = acc[mi][ni][r] + bv;
      }
    }
  }
}

// ---------------- flash attention: 4 waves x 32 q-rows, KVBLK=64 ----------------
__global__ __launch_bounds__(256, 2) void k_attn(
    const __bf16* __restrict__ qb, const __bf16* __restrict__ kb,
    const __bf16* __restrict__ vtb, __bf16* __restrict__ zb) {
  __shared__ __bf16 Ks[64 * 128];   // [kv][d], swizzled
  __shared__ __bf16 Vs[128 * 64];   // [d][kv], swizzled
  __shared__ __bf16 Ps[4 * 32 * 64];  // per-wave P, swizzled

  const int lane = threadIdx.x & 63, w = threadIdx.x >> 6;
  const int lm = lane >> 4, ln = lane & 15;
  const int qt = blockIdx.x & 15;
  const int bh = blockIdx.x >> 4;
  const int qw = qt * 128 + w * 32;  // wave's first q row

  const __bf16* qp = qb + (size_t)bh * S * D;
  const __bf16* kp = kb + (size_t)bh * S * D;
  const __bf16* vp = vtb + (size_t)bh * D * S;
  char* pw = (char*)Ps + w * 4096;

  bf16x8 qf[2][4];
#pragma unroll
  for (int mi = 0; mi < 2; ++mi)
#pragma unroll
    for (int kf = 0; kf < 4; ++kf)
      qf[mi][kf] = *reinterpret_cast<const bf16x8*>(qp + (qw + mi * 16 + ln) * D + kf * 32 + lm * 8);

  f32x4 Oa[2][8] = {};
  float mrow[2][4], lrow[2][4];
#pragma unroll
  for (int mi = 0; mi < 2; ++mi)
#pragma unroll
    for (int r = 0; r < 4; ++r) { mrow[mi][r] = -3.0e38f; lrow[mi][r] = 0.0f; }

  const int ktEnd = 2 * qt + 1;
  for (int kt = 0; kt <= ktEnd; ++kt) {
    const int kv0 = kt * 64;
    __syncthreads();
#pragma unroll
    for (int j = 0; j < 4; ++j) {  // K tile: 64 rows x 256B
      int base = (w * 4 + j) * 64;
      int cidx = base + lane;
      int row = cidx >> 4;
      int ps = (cidx & 15) ^ (row & 7);
      gll16(kp + (size_t)(kv0 + row) * D + ps * 8, (char*)Ks + base * 16);
    }
#pragma unroll
    for (int j = 0; j < 4; ++j) {  // V^T tile: 128 rows x 128B
      int base = (w * 4 + j) * 64;
      int cidx = base + lane;
      int row = cidx >> 3;
      int ps = (cidx & 7) ^ (row & 7);
      gll16(vp + (size_t)row * S + kv0 + ps * 8, (char*)Vs + base * 16);
    }
    __syncthreads();
    if (kv0 > qw + 31) continue;  // fully masked for this wave
    const bool diag = (kv0 + 63 > qw);

    // S = Q K^T : M=32(q) N=64(kv) K=128(d)
    f32x4 sacc[2][4] = {};
#pragma unroll
    for (int kf = 0; kf < 4; ++kf) {
      bf16x8 kfr[4];
#pragma unroll
      for (int ni = 0; ni < 4; ++ni) {
        int row = ni * 16 + ln;
        int ch = (kf * 4 + lm) ^ (row & 7);
        kfr[ni] = *reinterpret_cast<const bf16x8*>((const char*)Ks + row * 256 + ch * 16);
      }
#pragma unroll
      for (int mi = 0; mi < 2; ++mi)
#pragma unroll
        for (int ni = 0; ni < 4; ++ni)
          sacc[mi][ni] = mfma16(qf[mi][kf], kfr[ni], sacc[mi][ni]);
    }

    if (diag) {
#pragma unroll
      for (int ni = 0; ni < 4; ++ni) {
        int c = kv0 + ni * 16 + ln;
#pragma unroll
        for (int mi = 0; mi < 2; ++mi) {
          int q0r = qw + mi * 16 + lm * 4;
#pragma unroll
          for (int r = 0; r < 4; ++r)
            if (c > q0r + r) sacc[mi][ni][r] = -1e30f;
        }
      }
    }

    // online softmax (row = (lm*4+r); cols split across 16 lanes)
#pragma unroll
    for (int mi = 0; mi < 2; ++mi)
#pragma unroll
      for (int r = 0; r < 4; ++r) {
        float mx = fmaxf(fmaxf(sacc[mi][0][r], sacc[mi][1][r]),
                         fmaxf(sacc[mi][2][r], sacc[mi][3][r]));
        mx = fmaxf(mx, __shfl_xor(mx, 1, 64));
        mx = fmaxf(mx, __shfl_xor(mx, 2, 64));
        mx = fmaxf(mx, __shfl_xor(mx, 4, 64));
        mx = fmaxf(mx, __shfl_xor(mx, 8, 64));
        float mnew = fmaxf(mrow[mi][r], mx);
        float corr = __expf(mrow[mi][r] - mnew);
        mrow[mi][r] = mnew;
        float rs = 0.0f;
#pragma unroll
        for (int ni = 0; ni < 4; ++ni) {
          float p = __expf(sacc[mi][ni][r] - mnew);
          sacc[mi][ni][r] = p;
          rs += p;
        }
        lrow[mi][r] = lrow[mi][r] * corr + rs;  // lane-partial row sum
#pragma unroll
        for (int ni = 0; ni < 8; ++ni) Oa[mi][ni][r] *= corr;
      }

    // P (C-layout) -> per-wave LDS (swizzled) -> A-layout frags
#pragma unroll
    for (int mi = 0; mi < 2; ++mi)
#pragma unroll
      for (int ni = 0; ni < 4; ++ni)
#pragma unroll
        for (int r = 0; r < 4; ++r) {
          int row = mi * 16 + lm * 4 + r;
          int bo = (row * 128 + (ni * 16 + ln) * 2) ^ ((row & 7) << 4);
          *reinterpret_cast<__bf16*>(pw + bo) = (__bf16)sacc[mi][ni][r];
        }

    asm volatile("s_waitcnt lgkmcnt(0)" ::: "memory");
    __builtin_amdgcn_sched_barrier(0);

    // O += P V : M=32(q) N=128(d) K=64(kv)
#pragma unroll
    for (int kf = 0; kf < 2; ++kf) {
      bf16x8 pfr[2], vfr[8];
#pragma unroll
      for (int mi = 0; mi < 2; ++mi) {
        int row = mi * 16 + ln;
        int ch = (kf * 4 + lm) ^ (row & 7);
        pfr[mi] = *reinterpret_cast<const bf16x8*>(pw + row * 128 + ch * 16);
      }
#pragma unroll
      for (int ni = 0; ni < 8; ++ni) {
        int row = ni * 16 + ln;  // d
        int ch = (kf * 4 + lm) ^ (row & 7);
        vfr[ni] = *reinterpret_cast<const bf16x8*>((const char*)Vs + row * 128 + ch * 16);
      }
#pragma unroll
      for (int mi = 0; mi < 2; ++mi)
#pragma unroll
        for (int ni = 0; ni < 8; ++ni)
          Oa[mi][ni] = mfma16(pfr[mi], vfr[ni], Oa[mi][ni]);
    }
  }

  // finish: reduce row sums across 16 lanes, normalize, write merged z
#pragma unroll
  for (int mi = 0; mi < 2; ++mi)
#pragma unroll
    for (int r = 0; r < 4; ++r) {
      float ls = lrow[mi][r];
      ls += __shfl_xor(ls, 1, 64);
      ls += __shfl_xor(ls, 2, 64);
      ls += __shfl_xor(ls, 4, 64);
      ls += __shfl_xor(ls, 8, 64);
      lrow[mi][r] = 1.0f / ls;
    }
  const int b = bh >> 4, h = bh & 15;
#pragma unroll
  for (int mi = 0; mi < 2; ++mi)
#pragma unroll
    for (int ni = 0; ni < 8; ++ni) {
      int d = ni * 16 + ln;
#pragma unroll
      for (int r = 0; r < 4; ++r) {
        int qrow = qw + mi * 16 + lm * 4 + r;
        zb[(size_t)(b * S + qrow) * F + h * D + d] = (__bf16)(Oa[mi][ni][r] * lrow[mi][r]);
      }
    }
}

// ---------------- launch ----------------
extern "C" void kernel_launch(void* const* d_in, const int* in_sizes, int n_in,
                              void* d_out, int out_size, void* d_ws, size_t ws_size,
                              hipStream_t stream) {
  const float* x = (const float*)d_in[0];
  // d_in[1] = causal mask (implemented analytically)
  const float* w_attn = (const float*)d_in[2];
  const float* b_attn = (const float*)d_in[3];
  const float* w_proj = (const float*)d_in[4];
  const float* b_proj = (const float*)d_in[5];
  float* out = (float*)d_out;

  char* ws = (char*)d_ws;
  __bf16* xb    = (__bf16*)(ws + 0);          // 16 MB  [4096][2048] (reused as zb)
  __bf16* wqkv  = (__bf16*)(ws + 16777216);   // 24 MB  [6144][2048] (W^T)
  __bf16* wpro  = (__bf16*)(ws + 41943040);   //  8 MB  [2048][2048] (W^T)
  __bf16* qb    = (__bf16*)(ws + 50331648);   // 16 MB  [bh][s][d]
  __bf16* kb    = (__bf16*)(ws + 67108864);   // 16 MB  [bh][s][d]
  __bf16* vtb   = (__bf16*)(ws + 83886080);   // 16 MB  [bh][d][s]
  __bf16* zb    = xb;  // x fully consumed by GEMM1 before attention writes z

  k_cvt<<<8192, 256, 0, stream>>>(x, xb);
  k_transpose<<<dim3(96, 32), 256, 0, stream>>>(w_attn, wqkv, 2048, 6144);
  k_transpose<<<dim3(32, 32), 256, 0, stream>>>(w_proj, wpro, 2048, 2048);
  k_gemm<0><<<dim3(48, 32), 256, 0, stream>>>(xb, wqkv, b_attn, qb, kb, vtb, nullptr);
  k_attn<<<512, 256, 0, stream>>>(qb, kb, vtb, zb);
  k_gemm<1><<<dim3(16, 32), 256, 0, stream>>>(zb, wpro, b_proj, nullptr, nullptr, nullptr, out);
}

// Round 2
// 305.674 us; speedup vs baseline: 1.0319x; 1.0319x over previous
//
#include <hip/hip_runtime.h>
#include <hip/hip_bf16.h>
#include <stdint.h>

typedef __attribute__((ext_vector_type(8))) __bf16 bf16x8;
typedef __attribute__((ext_vector_type(4))) __bf16 bf16x4;
typedef __attribute__((ext_vector_type(4))) float f32x4;

#define DEV __device__ __forceinline__

static constexpr int S = 2048, F = 2048, H = 16, D = 128;
static constexpr int KDIM = F;            // 2048
static constexpr float QSCALE = 0.08838834764831845f;  // 1/sqrt(128)

DEV void gll16(const void* g, void* l) {
  __builtin_amdgcn_global_load_lds(
      (const __attribute__((address_space(1))) void*)g,
      (__attribute__((address_space(3))) void*)l, 16, 0, 0);
}

DEV f32x4 mfma16(bf16x8 a, bf16x8 b, f32x4 c) {
  return __builtin_amdgcn_mfma_f32_16x16x32_bf16(a, b, c, 0, 0, 0);
}

// ---------------- elementwise f32 -> bf16 ----------------
__global__ void k_cvt(const float* __restrict__ in, __bf16* __restrict__ out) {
  int i = blockIdx.x * 256 + threadIdx.x;
  float4 v = reinterpret_cast<const float4*>(in)[i];
  bf16x4 o = {(__bf16)v.x, (__bf16)v.y, (__bf16)v.z, (__bf16)v.w};
  reinterpret_cast<bf16x4*>(out)[i] = o;
}

// ---------------- transpose f32 [rows][cols] -> bf16 [cols][rows] ----------------
__global__ void k_transpose(const float* __restrict__ in, __bf16* __restrict__ out,
                            int rows, int cols) {
  __shared__ float t[64][65];
  const int c0 = blockIdx.x * 64, r0 = blockIdx.y * 64;
  const int tx = threadIdx.x & 63, ty = threadIdx.x >> 6;
#pragma unroll
  for (int i = 0; i < 64; i += 4)
    t[ty + i][tx] = in[(size_t)(r0 + ty + i) * cols + c0 + tx];
  __syncthreads();
#pragma unroll
  for (int i = 0; i < 64; i += 4)
    out[(size_t)(c0 + ty + i) * rows + r0 + tx] = (__bf16)t[tx][ty + i];
}

// ================= 256x256 8-phase GEMM (QKV) =================
// C[M,N] = A[M,K] * Bt[N,K]^T + bias, routed to Q (scaled), K, V^T bf16 buffers.
// 8 waves (2M x 4N), wave tile 128x64, BK=64, 128 KiB LDS double-buffer.
// LDS map: buf c @ c*65536; A-half h @ h*16384; B-half h @ 32768 + h*16384.
// Half = [128 rows][64 cols bf16] row-major, chunk-swizzled: 16B slot cc of row r
// holds logical cols (cc ^ (r&7))*8.. (source pre-swizzled for global_load_lds).
extern __shared__ char smem[];

template <int MH, int NH>
DEV void qmfma(f32x4 (&acc)[8][4], const bf16x8 (&af)[4][2], const bf16x8 (&bf)[2][2]) {
#pragma unroll
  for (int ks = 0; ks < 2; ++ks)
#pragma unroll
    for (int mi = 0; mi < 4; ++mi)
#pragma unroll
      for (int ni = 0; ni < 2; ++ni)
        acc[MH * 4 + mi][NH * 2 + ni] =
            mfma16(af[mi][ks], bf[ni][ks], acc[MH * 4 + mi][NH * 2 + ni]);
}

__global__ __launch_bounds__(512, 2) void k_gemm8(
    const __bf16* __restrict__ A, const __bf16* __restrict__ Bt,
    const float* __restrict__ bias,
    __bf16* __restrict__ qo, __bf16* __restrict__ ko, __bf16* __restrict__ vo,
    int nbx) {
  const int tid = threadIdx.x;
  const int lane = tid & 63, wid = tid >> 6;
  const int wm = wid >> 2, wn = wid & 3;
  const int ln = lane & 15, lm = lane >> 4;

  // T1: XCD-aware bijective swizzle (gridDim.x % 8 == 0)
  const int q8 = gridDim.x >> 3;
  const int lin = (blockIdx.x & 7) * q8 + (blockIdx.x >> 3);
  const int bx = lin % nbx, by = lin / nbx;
  const int mBase = by * 256, nBase = bx * 256;

  // staging: chunk c = j*512 + tid covers LDS bytes c*16 of a 16 KiB half-tile
  int srcS[2], ldsOff[2];
#pragma unroll
  for (int j = 0; j < 2; ++j) {
    int c = j * 512 + tid;
    int r = c >> 3, cc = c & 7;
    int ps = cc ^ (r & 7);
    srcS[j] = r * KDIM + ps * 8;        // elements
    ldsOff[j] = j * 8192 + wid * 1024;  // bytes (wave-uniform base + lane*16)
  }
  const __bf16* Abase = A + (size_t)mBase * KDIM;
  const __bf16* Bbase = Bt + (size_t)nBase * KDIM;

  auto stageA = [&](int buf, int h, int t) {
#pragma unroll
    for (int j = 0; j < 2; ++j)
      gll16(Abase + (size_t)h * 128 * KDIM + t * 64 + srcS[j],
            smem + buf * 65536 + h * 16384 + ldsOff[j]);
  };
  auto stageB = [&](int buf, int h, int t) {
#pragma unroll
    for (int j = 0; j < 2; ++j)
      gll16(Bbase + (size_t)h * 128 * KDIM + t * 64 + srcS[j],
            smem + buf * 65536 + 32768 + h * 16384 + ldsOff[j]);
  };

  // ds_read lane offsets (XOR-swizzled chunk; independent of frag index)
  int loA[2], loB[2];
#pragma unroll
  for (int ks = 0; ks < 2; ++ks) {
    int slot = (ks * 4 + lm) ^ (ln & 7);
    loA[ks] = (wm * 16 + ln) * 128 + slot * 16;
    loB[ks] = (wn * 16 + ln) * 128 + slot * 16;
  }
  auto loadA = [&](bf16x8 (&af)[4][2], int buf, int h) {
    const char* base = smem + buf * 65536 + h * 16384;
#pragma unroll
    for (int mi = 0; mi < 4; ++mi)
#pragma unroll
      for (int ks = 0; ks < 2; ++ks)
        af[mi][ks] = *reinterpret_cast<const bf16x8*>(base + mi * 4096 + loA[ks]);
  };
  auto loadB = [&](bf16x8 (&bf)[2][2], int buf, int h) {
    const char* base = smem + buf * 65536 + 32768 + h * 16384;
#pragma unroll
    for (int ni = 0; ni < 2; ++ni)
#pragma unroll
      for (int ks = 0; ks < 2; ++ks)
        bf[ni][ks] = *reinterpret_cast<const bf16x8*>(base + ni * 8192 + loB[ks]);
  };

  f32x4 acc[8][4] = {};
  bf16x8 af[4][2], b0[2][2], b1[2][2];

  // prologue: tile0 (4 halves) + A0(1), B1(1); vmcnt(4) => tile0 landed
  stageA(0, 0, 0); stageB(0, 0, 0); stageA(0, 1, 0); stageB(0, 1, 0);
  stageA(1, 0, 1); stageB(1, 1, 1);
  asm volatile("s_waitcnt vmcnt(4)" ::: "memory");
  __builtin_amdgcn_s_barrier();

  const int NT = KDIM / 64;  // 32
  for (int t = 0; t < NT; ++t) {
    const int cur = t & 1, nxt = cur ^ 1;
    // ---- phase 0: Q(0,0); stage A1(t+1) [slot A1(t-1): dead] ----
    loadA(af, cur, 0);
    loadB(b0, cur, 0);
    if (t + 1 < NT) stageA(nxt, 1, t + 1);
    __builtin_amdgcn_s_barrier();
    asm volatile("s_waitcnt lgkmcnt(0)" ::: "memory");
    __builtin_amdgcn_sched_barrier(0);
    __builtin_amdgcn_s_setprio(1);
    qmfma<0, 0>(acc, af, b0);
    __builtin_amdgcn_s_setprio(0);
    __builtin_amdgcn_s_barrier();
    // ---- phase 1: Q(0,1); stage B0(t+1) [slot B0(t-1): dead] ----
    loadB(b1, cur, 1);
    if (t + 1 < NT) stageB(nxt, 0, t + 1);
    __builtin_amdgcn_s_barrier();
    asm volatile("s_waitcnt lgkmcnt(0)" ::: "memory");
    __builtin_amdgcn_sched_barrier(0);
    __builtin_amdgcn_s_setprio(1);
    qmfma<0, 1>(acc, af, b1);
    __builtin_amdgcn_s_setprio(0);
    __builtin_amdgcn_s_barrier();
    // ---- phase 2: Q(1,1); stage A0(t+2) [A0(t) last read at p0] ----
    loadA(af, cur, 1);
    if (t + 2 < NT) stageA(cur, 0, t + 2);
    __builtin_amdgcn_s_barrier();
    asm volatile("s_waitcnt lgkmcnt(0)" ::: "memory");
    __builtin_amdgcn_sched_barrier(0);
    __builtin_amdgcn_s_setprio(1);
    qmfma<1, 1>(acc, af, b1);
    __builtin_amdgcn_s_setprio(0);
    __builtin_amdgcn_s_barrier();
    // ---- phase 3: Q(1,0); stage B1(t+2) [B1(t) last read at p1] ----
    if (t + 2 < NT) stageB(cur, 1, t + 2);
    __builtin_amdgcn_s_barrier();
    __builtin_amdgcn_sched_barrier(0);
    __builtin_amdgcn_s_setprio(1);
    qmfma<1, 0>(acc, af, b0);
    __builtin_amdgcn_s_setprio(0);
    if (t < NT - 2)
      asm volatile("s_waitcnt vmcnt(4)" ::: "memory");  // tile t+1 fully landed
    else
      asm volatile("s_waitcnt vmcnt(0)" ::: "memory");  // drain at the end
    __builtin_amdgcn_s_barrier();
  }

  // epilogue: route Q (scaled), K, V^T
  const int sec = nBase >> 11;  // 256 | 2048, tile never crosses a section
#pragma unroll
  for (int mi = 0; mi < 8; ++mi) {
    const int grow = mBase + (mi >> 2) * 128 + (mi & 3) * 32 + wm * 16 + lm * 4;
    const int b = grow >> 11;
    const int s0 = grow & 2047;
#pragma unroll
    for (int ni = 0; ni < 4; ++ni) {
      const int gcol = nBase + (ni >> 1) * 128 + (ni & 1) * 64 + wn * 16 + ln;
      const float bv = bias[gcol];
      const int h = (gcol >> 7) & 15;
      const int d = gcol & 127;
      const int bh = b * H + h;
      if (sec == 0) {
#pragma unroll
        for (int r = 0; r < 4; ++r)
          qo[((size_t)bh * S + s0 + r) * D + d] = (__bf16)((acc[mi][ni][r] + bv) * QSCALE);
      } else if (sec == 1) {
#pragma unroll
        for (int r = 0; r < 4; ++r)
          ko[((size_t)bh * S + s0 + r) * D + d] = (__bf16)(acc[mi][ni][r] + bv);
      } else {
        bf16x4 pv = {(__bf16)(acc[mi][ni][0] + bv), (__bf16)(acc[mi][ni][1] + bv),
                     (__bf16)(acc[mi][ni][2] + bv), (__bf16)(acc[mi][ni][3] + bv)};
        *reinterpret_cast<bf16x4*>(vo + ((size_t)bh * D + d) * S + s0) = pv;  // V^T
      }
    }
  }
}

// ---------------- GEMM: C[M,N] = A[M,K] * Bt[N,K]^T (+bias), f32 out ----------------
// 128x128 tile, BK=32, 256 thr (4 waves 2x2). Used for the out-projection.
template <int EPI>
__global__ __launch_bounds__(256, 2) void k_gemm(
    const __bf16* __restrict__ A, const __bf16* __restrict__ Bt,
    const float* __restrict__ bias, float* __restrict__ fo) {
  __shared__ __bf16 As[128 * 32];
  __shared__ __bf16 Bs[128 * 32];
  const int lane = threadIdx.x & 63, w = threadIdx.x >> 6;
  const int wm = w >> 1, wn = w & 1;
  const int lm = lane >> 4, ln = lane & 15;
  const int mBase = blockIdx.y * 128, nBase = blockIdx.x * 128;

  f32x4 acc[4][4] = {};

  for (int k0 = 0; k0 < KDIM; k0 += 32) {
    __syncthreads();
#pragma unroll
    for (int j = 0; j < 2; ++j) {
      int cidx = (w * 2 + j) * 64 + lane;
      int row = cidx >> 2;
      int ps = (cidx & 3) ^ ((row >> 1) & 3);
      gll16(A + (size_t)(mBase + row) * KDIM + k0 + ps * 8, (char*)As + (w * 2 + j) * 1024);
      gll16(Bt + (size_t)(nBase + row) * KDIM + k0 + ps * 8, (char*)Bs + (w * 2 + j) * 1024);
    }
    __syncthreads();
    bf16x8 af[4], bfr[4];
#pragma unroll
    for (int mi = 0; mi < 4; ++mi) {
      int row = wm * 64 + mi * 16 + ln;
      int q = lm ^ ((row >> 1) & 3);
      af[mi] = *reinterpret_cast<const bf16x8*>((const char*)As + row * 64 + q * 16);
    }
#pragma unroll
    for (int ni = 0; ni < 4; ++ni) {
      int row = wn * 64 + ni * 16 + ln;
      int q = lm ^ ((row >> 1) & 3);
      bfr[ni] = *reinterpret_cast<const bf16x8*>((const char*)Bs + row * 64 + q * 16);
    }
#pragma unroll
    for (int mi = 0; mi < 4; ++mi)
#pragma unroll
      for (int ni = 0; ni < 4; ++ni)
        acc[mi][ni] = mfma16(af[mi], bfr[ni], acc[mi][ni]);
  }

#pragma unroll
  for (int mi = 0; mi < 4; ++mi) {
    const int m0 = mBase + wm * 64 + mi * 16 + lm * 4;
#pragma unroll
    for (int ni = 0; ni < 4; ++ni) {
      const int nG = nBase + wn * 64 + ni * 16 + ln;
      const float bv = bias[nG];
#pragma unroll
      for (int r = 0; r < 4; ++r)
        fo[(size_t)(m0 + r) * F + nG] = acc[mi][ni][r] + bv;
    }
  }
}

// ---------------- flash attention: 4 waves x 32 q-rows, KVBLK=64 ----------------
__global__ __launch_bounds__(256, 2) void k_attn(
    const __bf16* __restrict__ qb, const __bf16* __restrict__ kb,
    const __bf16* __restrict__ vtb, __bf16* __restrict__ zb) {
  __shared__ __bf16 Ks[64 * 128];   // [kv][d], swizzled
  __shared__ __bf16 Vs[128 * 64];   // [d][kv], swizzled
  __shared__ __bf16 Ps[4 * 32 * 64];  // per-wave P, swizzled

  const int lane = threadIdx.x & 63, w = threadIdx.x >> 6;
  const int lm = lane >> 4, ln = lane & 15;
  const int qt = blockIdx.x & 15;
  const int bh = blockIdx.x >> 4;
  const int qw = qt * 128 + w * 32;  // wave's first q row

  const __bf16* qp = qb + (size_t)bh * S * D;
  const __bf16* kp = kb + (size_t)bh * S * D;
  const __bf16* vp = vtb + (size_t)bh * D * S;
  char* pw = (char*)Ps + w * 4096;

  bf16x8 qf[2][4];
#pragma unroll
  for (int mi = 0; mi < 2; ++mi)
#pragma unroll
    for (int kf = 0; kf < 4; ++kf)
      qf[mi][kf] = *reinterpret_cast<const bf16x8*>(qp + (qw + mi * 16 + ln) * D + kf * 32 + lm * 8);

  f32x4 Oa[2][8] = {};
  float mrow[2][4], lrow[2][4];
#pragma unroll
  for (int mi = 0; mi < 2; ++mi)
#pragma unroll
    for (int r = 0; r < 4; ++r) { mrow[mi][r] = -3.0e38f; lrow[mi][r] = 0.0f; }

  const int ktEnd = 2 * qt + 1;
  for (int kt = 0; kt <= ktEnd; ++kt) {
    const int kv0 = kt * 64;
    __syncthreads();
#pragma unroll
    for (int j = 0; j < 4; ++j) {  // K tile: 64 rows x 256B
      int base = (w * 4 + j) * 64;
      int cidx = base + lane;
      int row = cidx >> 4;
      int ps = (cidx & 15) ^ (row & 7);
      gll16(kp + (size_t)(kv0 + row) * D + ps * 8, (char*)Ks + base * 16);
    }
#pragma unroll
    for (int j = 0; j < 4; ++j) {  // V^T tile: 128 rows x 128B
      int base = (w * 4 + j) * 64;
      int cidx = base + lane;
      int row = cidx >> 3;
      int ps = (cidx & 7) ^ (row & 7);
      gll16(vp + (size_t)row * S + kv0 + ps * 8, (char*)Vs + base * 16);
    }
    __syncthreads();
    if (kv0 > qw + 31) continue;  // fully masked for this wave
    const bool diag = (kv0 + 63 > qw);

    // S = Q K^T : M=32(q) N=64(kv) K=128(d)
    f32x4 sacc[2][4] = {};
#pragma unroll
    for (int kf = 0; kf < 4; ++kf) {
      bf16x8 kfr[4];
#pragma unroll
      for (int ni = 0; ni < 4; ++ni) {
        int row = ni * 16 + ln;
        int ch = (kf * 4 + lm) ^ (row & 7);
        kfr[ni] = *reinterpret_cast<const bf16x8*>((const char*)Ks + row * 256 + ch * 16);
      }
#pragma unroll
      for (int mi = 0; mi < 2; ++mi)
#pragma unroll
        for (int ni = 0; ni < 4; ++ni)
          sacc[mi][ni] = mfma16(qf[mi][kf], kfr[ni], sacc[mi][ni]);
    }

    if (diag) {
#pragma unroll
      for (int ni = 0; ni < 4; ++ni) {
        int c = kv0 + ni * 16 + ln;
#pragma unroll
        for (int mi = 0; mi < 2; ++mi) {
          int q0r = qw + mi * 16 + lm * 4;
#pragma unroll
          for (int r = 0; r < 4; ++r)
            if (c > q0r + r) sacc[mi][ni][r] = -1e30f;
        }
      }
    }

    // online softmax (row = (lm*4+r); cols split across 16 lanes)
#pragma unroll
    for (int mi = 0; mi < 2; ++mi)
#pragma unroll
      for (int r = 0; r < 4; ++r) {
        float mx = fmaxf(fmaxf(sacc[mi][0][r], sacc[mi][1][r]),
                         fmaxf(sacc[mi][2][r], sacc[mi][3][r]));
        mx = fmaxf(mx, __shfl_xor(mx, 1, 64));
        mx = fmaxf(mx, __shfl_xor(mx, 2, 64));
        mx = fmaxf(mx, __shfl_xor(mx, 4, 64));
        mx = fmaxf(mx, __shfl_xor(mx, 8, 64));
        float mnew = fmaxf(mrow[mi][r], mx);
        float corr = __expf(mrow[mi][r] - mnew);
        mrow[mi][r] = mnew;
        float rs = 0.0f;
#pragma unroll
        for (int ni = 0; ni < 4; ++ni) {
          float p = __expf(sacc[mi][ni][r] - mnew);
          sacc[mi][ni][r] = p;
          rs += p;
        }
        lrow[mi][r] = lrow[mi][r] * corr + rs;  // lane-partial row sum
#pragma unroll
        for (int ni = 0; ni < 8; ++ni) Oa[mi][ni][r] *= corr;
      }

    // P (C-layout) -> per-wave LDS (swizzled) -> A-layout frags
#pragma unroll
    for (int mi = 0; mi < 2; ++mi)
#pragma unroll
      for (int ni = 0; ni < 4; ++ni)
#pragma unroll
        for (int r = 0; r < 4; ++r) {
          int row = mi * 16 + lm * 4 + r;
          int bo = (row * 128 + (ni * 16 + ln) * 2) ^ ((row & 7) << 4);
          *reinterpret_cast<__bf16*>(pw + bo) = (__bf16)sacc[mi][ni][r];
        }

    asm volatile("s_waitcnt lgkmcnt(0)" ::: "memory");
    __builtin_amdgcn_sched_barrier(0);

    // O += P V : M=32(q) N=128(d) K=64(kv)
#pragma unroll
    for (int kf = 0; kf < 2; ++kf) {
      bf16x8 pfr[2], vfr[8];
#pragma unroll
      for (int mi = 0; mi < 2; ++mi) {
        int row = mi * 16 + ln;
        int ch = (kf * 4 + lm) ^ (row & 7);
        pfr[mi] = *reinterpret_cast<const bf16x8*>(pw + row * 128 + ch * 16);
      }
#pragma unroll
      for (int ni = 0; ni < 8; ++ni) {
        int row = ni * 16 + ln;  // d
        int ch = (kf * 4 + lm) ^ (row & 7);
        vfr[ni] = *reinterpret_cast<const bf16x8*>((const char*)Vs + row * 128 + ch * 16);
      }
#pragma unroll
      for (int mi = 0; mi < 2; ++mi)
#pragma unroll
        for (int ni = 0; ni < 8; ++ni)
          Oa[mi][ni] = mfma16(pfr[mi], vfr[ni], Oa[mi][ni]);
    }
  }

  // finish: reduce row sums across 16 lanes, normalize, write merged z
#pragma unroll
  for (int mi = 0; mi < 2; ++mi)
#pragma unroll
    for (int r = 0; r < 4; ++r) {
      float ls = lrow[mi][r];
      ls += __shfl_xor(ls, 1, 64);
      ls += __shfl_xor(ls, 2, 64);
      ls += __shfl_xor(ls, 4, 64);
      ls += __shfl_xor(ls, 8, 64);
      lrow[mi][r] = 1.0f / ls;
    }
  const int b = bh >> 4, h = bh & 15;
#pragma unroll
  for (int mi = 0; mi < 2; ++mi)
#pragma unroll
    for (int ni = 0; ni < 8; ++ni) {
      int d = ni * 16 + ln;
#pragma unroll
      for (int r = 0; r < 4; ++r) {
        int qrow = qw + mi * 16 + lm * 4 + r;
        zb[(size_t)(b * S + qrow) * F + h * D + d] = (__bf16)(Oa[mi][ni][r] * lrow[mi][r]);
      }
    }
}

// ---------------- launch ----------------
extern "C" void kernel_launch(void* const* d_in, const int* in_sizes, int n_in,
                              void* d_out, int out_size, void* d_ws, size_t ws_size,
                              hipStream_t stream) {
  const float* x = (const float*)d_in[0];
  // d_in[1] = causal mask (implemented analytically)
  const float* w_attn = (const float*)d_in[2];
  const float* b_attn = (const float*)d_in[3];
  const float* w_proj = (const float*)d_in[4];
  const float* b_proj = (const float*)d_in[5];
  float* out = (float*)d_out;

  char* ws = (char*)d_ws;
  __bf16* xb    = (__bf16*)(ws + 0);          // 16 MB  [4096][2048] (reused as zb)
  __bf16* wqkv  = (__bf16*)(ws + 16777216);   // 24 MB  [6144][2048] (W^T)
  __bf16* wpro  = (__bf16*)(ws + 41943040);   //  8 MB  [2048][2048] (W^T)
  __bf16* qb    = (__bf16*)(ws + 50331648);   // 16 MB  [bh][s][d]
  __bf16* kb    = (__bf16*)(ws + 67108864);   // 16 MB  [bh][s][d]
  __bf16* vtb   = (__bf16*)(ws + 83886080);   // 16 MB  [bh][d][s]
  __bf16* zb    = xb;  // x fully consumed by QKV GEMM before attention writes z

  (void)hipFuncSetAttribute((const void*)k_gemm8,
                            hipFuncAttributeMaxDynamicSharedMemorySize, 131072);

  k_cvt<<<8192, 256, 0, stream>>>(x, xb);
  k_transpose<<<dim3(96, 32), 256, 0, stream>>>(w_attn, wqkv, 2048, 6144);
  k_transpose<<<dim3(32, 32), 256, 0, stream>>>(w_proj, wpro, 2048, 2048);
  // QKV: M=4096, N=6144 -> grid 16x24 = 384 blocks (x-linearized, XCD-swizzled)
  k_gemm8<<<384, 512, 131072, stream>>>(xb, wqkv, b_attn, qb, kb, vtb, 24);
  k_attn<<<512, 256, 0, stream>>>(qb, kb, vtb, zb);
  k_gemm<1><<<dim3(16, 32), 256, 0, stream>>>(zb, wpro, b_proj, out);
}

// Round 3
// 274.487 us; speedup vs baseline: 1.1491x; 1.1136x over previous
//
#include <hip/hip_runtime.h>
#include <hip/hip_bf16.h>
#include <stdint.h>

typedef __attribute__((ext_vector_type(8))) __bf16 bf16x8;
typedef __attribute__((ext_vector_type(4))) __bf16 bf16x4;
typedef __attribute__((ext_vector_type(4))) float f32x4;

#define DEV __device__ __forceinline__

static constexpr int S = 2048, F = 2048, H = 16, D = 128;
static constexpr int KDIM = F;            // 2048
static constexpr float QSCALE = 0.08838834764831845f;  // 1/sqrt(128)

DEV void gll16(const void* g, void* l) {
  __builtin_amdgcn_global_load_lds(
      (const __attribute__((address_space(1))) void*)g,
      (__attribute__((address_space(3))) void*)l, 16, 0, 0);
}

DEV f32x4 mfma16(bf16x8 a, bf16x8 b, f32x4 c) {
  return __builtin_amdgcn_mfma_f32_16x16x32_bf16(a, b, c, 0, 0, 0);
}

extern __shared__ char smem[];

// ---------------- elementwise f32 -> bf16 ----------------
__global__ void k_cvt(const float* __restrict__ in, __bf16* __restrict__ out) {
  int i = blockIdx.x * 256 + threadIdx.x;
  float4 v = reinterpret_cast<const float4*>(in)[i];
  bf16x4 o = {(__bf16)v.x, (__bf16)v.y, (__bf16)v.z, (__bf16)v.w};
  reinterpret_cast<bf16x4*>(out)[i] = o;
}

// ---------------- transpose f32 [rows][cols] -> bf16 [cols][rows] ----------------
__global__ void k_transpose(const float* __restrict__ in, __bf16* __restrict__ out,
                            int rows, int cols) {
  __shared__ float t[64][65];
  const int c0 = blockIdx.x * 64, r0 = blockIdx.y * 64;
  const int tx = threadIdx.x & 63, ty = threadIdx.x >> 6;
#pragma unroll
  for (int i = 0; i < 64; i += 4)
    t[ty + i][tx] = in[(size_t)(r0 + ty + i) * cols + c0 + tx];
  __syncthreads();
#pragma unroll
  for (int i = 0; i < 64; i += 4)
    out[(size_t)(c0 + ty + i) * rows + r0 + tx] = (__bf16)t[tx][ty + i];
}

// ================= 128x256 triple-buffered GEMM =================
// C[M,N] = A[M,K]*Bt[N,K]^T + bias. 8 waves (2M x 4N), wave tile 64x64, BK=64.
// LDS: 3 buffers x 48 KiB {A:[128][64] 16K, B:[256][64] 32K}, chunk-XOR swizzled.
// Prefetch depth 2 (stage t+2 while computing t) -> ONE barrier + vmcnt(6)/K-tile.
// EPI 0: route Q(scaled)/K/V^T bf16.  EPI 1: f32 +bias.
template <int EPI>
__global__ __launch_bounds__(512, 2) void k_gemm_tb(
    const __bf16* __restrict__ A, const __bf16* __restrict__ Bt,
    const float* __restrict__ bias,
    __bf16* __restrict__ qo, __bf16* __restrict__ ko, __bf16* __restrict__ vo,
    float* __restrict__ fo, int nbx) {
  const int tid = threadIdx.x;
  const int lane = tid & 63, wid = tid >> 6;
  const int wm = wid >> 2, wn = wid & 3;
  const int ln = lane & 15, lm = lane >> 4;

  // T1: XCD-aware bijective swizzle (gridDim.x % 8 == 0)
  const int q8 = gridDim.x >> 3;
  const int lin = (blockIdx.x & 7) * q8 + (blockIdx.x >> 3);
  const int bx = lin % nbx, by = lin / nbx;
  const int mBase = by * 128, nBase = bx * 256;

  // staging: chunk c covers LDS bytes c*16; source pre-swizzled (rule 21)
  int srcA[2], dstA[2], srcB[4], dstB[4];
#pragma unroll
  for (int j = 0; j < 2; ++j) {
    int c = j * 512 + tid, r = c >> 3, cc = c & 7;
    srcA[j] = r * KDIM + ((cc ^ (r & 7)) << 3);
    dstA[j] = j * 8192 + wid * 1024;  // wave-uniform base (+lane*16 by HW)
  }
#pragma unroll
  for (int j = 0; j < 4; ++j) {
    int c = j * 512 + tid, r = c >> 3, cc = c & 7;
    srcB[j] = r * KDIM + ((cc ^ (r & 7)) << 3);
    dstB[j] = 16384 + j * 8192 + wid * 1024;
  }
  const __bf16* Ab = A + (size_t)mBase * KDIM;
  const __bf16* Bb = Bt + (size_t)nBase * KDIM;

  // ds_read offsets: slot = logical-chunk ^ (row&7); row&7 == ln&7 here
  int loA[2], loB[2];
#pragma unroll
  for (int ks = 0; ks < 2; ++ks) {
    int slot = (ks * 4 + lm) ^ (ln & 7);
    loA[ks] = (wm * 64 + ln) * 128 + slot * 16;
    loB[ks] = 16384 + (wn * 64 + ln) * 128 + slot * 16;
  }

  f32x4 acc[4][4] = {};
  constexpr int NT = KDIM / 64;  // 32

  // prologue: stage tiles 0 and 1 (6 loads each)
#pragma unroll
  for (int j = 0; j < 2; ++j) gll16(Ab + srcA[j], smem + dstA[j]);
#pragma unroll
  for (int j = 0; j < 4; ++j) gll16(Bb + srcB[j], smem + dstB[j]);
#pragma unroll
  for (int j = 0; j < 2; ++j) gll16(Ab + 64 + srcA[j], smem + 49152 + dstA[j]);
#pragma unroll
  for (int j = 0; j < 4; ++j) gll16(Bb + 64 + srcB[j], smem + 49152 + dstB[j]);
  asm volatile("s_waitcnt vmcnt(6)" ::: "memory");  // tile 0 landed
  __builtin_amdgcn_s_barrier();
  __builtin_amdgcn_sched_barrier(0);

  for (int t = 0; t < NT; ++t) {
    const char* cbuf = smem + (t % 3) * 49152;
    char* nbuf = smem + ((t + 2) % 3) * 49152;
    const __bf16* Asrc = Ab + (t + 2) * 64;
    const __bf16* Bsrc = Bb + (t + 2) * 64;
    const bool pf = (t + 2 < NT);

    // ---- phase ks=0 ----
    bf16x8 af0[4], bf0[4];
#pragma unroll
    for (int mi = 0; mi < 4; ++mi)
      af0[mi] = *reinterpret_cast<const bf16x8*>(cbuf + mi * 2048 + loA[0]);
#pragma unroll
    for (int ni = 0; ni < 4; ++ni)
      bf0[ni] = *reinterpret_cast<const bf16x8*>(cbuf + ni * 2048 + loB[0]);
    if (pf) {
      gll16(Asrc + srcA[0], nbuf + dstA[0]);
      gll16(Asrc + srcA[1], nbuf + dstA[1]);
      gll16(Bsrc + srcB[0], nbuf + dstB[0]);
    }
    __builtin_amdgcn_s_setprio(1);
#pragma unroll
    for (int mi = 0; mi < 4; ++mi)
#pragma unroll
      for (int ni = 0; ni < 4; ++ni)
        acc[mi][ni] = mfma16(af0[mi], bf0[ni], acc[mi][ni]);
    __builtin_amdgcn_s_setprio(0);

    // ---- phase ks=1 ----
    bf16x8 af1[4], bf1[4];
#pragma unroll
    for (int mi = 0; mi < 4; ++mi)
      af1[mi] = *reinterpret_cast<const bf16x8*>(cbuf + mi * 2048 + loA[1]);
#pragma unroll
    for (int ni = 0; ni < 4; ++ni)
      bf1[ni] = *reinterpret_cast<const bf16x8*>(cbuf + ni * 2048 + loB[1]);
    if (pf) {
      gll16(Bsrc + srcB[1], nbuf + dstB[1]);
      gll16(Bsrc + srcB[2], nbuf + dstB[2]);
      gll16(Bsrc + srcB[3], nbuf + dstB[3]);
    }
    __builtin_amdgcn_s_setprio(1);
#pragma unroll
    for (int mi = 0; mi < 4; ++mi)
#pragma unroll
      for (int ni = 0; ni < 4; ++ni)
        acc[mi][ni] = mfma16(af1[mi], bf1[ni], acc[mi][ni]);
    __builtin_amdgcn_s_setprio(0);

    // ---- tile boundary: per-wave drain BEFORE barrier (publication) ----
    if (t < NT - 2)
      asm volatile("s_waitcnt vmcnt(6) lgkmcnt(0)" ::: "memory");
    else
      asm volatile("s_waitcnt vmcnt(0) lgkmcnt(0)" ::: "memory");
    __builtin_amdgcn_s_barrier();
    __builtin_amdgcn_sched_barrier(0);
  }

  if (EPI == 0) {
    const int sec = nBase >> 11;  // 2048-col sections: Q|K|V (8 tiles each)
#pragma unroll
    for (int mi = 0; mi < 4; ++mi) {
      const int grow = mBase + wm * 64 + mi * 16 + lm * 4;
      const int b = grow >> 11, s0 = grow & 2047;
#pragma unroll
      for (int ni = 0; ni < 4; ++ni) {
        const int gcol = nBase + wn * 64 + ni * 16 + ln;
        const float bv = bias[gcol];
        const int h = (gcol >> 7) & 15, d = gcol & 127;
        const int bh = b * H + h;
        if (sec == 0) {
#pragma unroll
          for (int r = 0; r < 4; ++r)
            qo[((size_t)bh * S + s0 + r) * D + d] = (__bf16)((acc[mi][ni][r] + bv) * QSCALE);
        } else if (sec == 1) {
#pragma unroll
          for (int r = 0; r < 4; ++r)
            ko[((size_t)bh * S + s0 + r) * D + d] = (__bf16)(acc[mi][ni][r] + bv);
        } else {
          bf16x4 pv = {(__bf16)(acc[mi][ni][0] + bv), (__bf16)(acc[mi][ni][1] + bv),
                       (__bf16)(acc[mi][ni][2] + bv), (__bf16)(acc[mi][ni][3] + bv)};
          *reinterpret_cast<bf16x4*>(vo + ((size_t)bh * D + d) * S + s0) = pv;  // V^T
        }
      }
    }
  } else {
#pragma unroll
    for (int mi = 0; mi < 4; ++mi) {
      const int grow = mBase + wm * 64 + mi * 16 + lm * 4;
#pragma unroll
      for (int ni = 0; ni < 4; ++ni) {
        const int gcol = nBase + wn * 64 + ni * 16 + ln;
        const float bv = bias[gcol];
#pragma unroll
        for (int r = 0; r < 4; ++r)
          fo[(size_t)(grow + r) * F + gcol] = acc[mi][ni][r] + bv;
      }
    }
  }
}

// ---------------- flash attention: 4 waves x 32 q-rows, KVBLK=64 ----------------
// Double-buffered K/V (2-phase pipeline), 1 barrier/tile. 80 KiB dynamic LDS:
// buf i @ i*32768 {K:[64][128] 16K, V^T:[128][64] 16K}, Ps @ 65536 + w*4096.
// Block remap: bh = bid&31 (XCD affinity: bid%8 const per bh), qt = 15-(bid>>5) (LPT).
__global__ __launch_bounds__(256, 2) void k_attn(
    const __bf16* __restrict__ qb, const __bf16* __restrict__ kb,
    const __bf16* __restrict__ vtb, __bf16* __restrict__ zb) {
  const int lane = threadIdx.x & 63, w = threadIdx.x >> 6;
  const int lm = lane >> 4, ln = lane & 15;
  const int blk = blockIdx.x;
  const int bh = blk & 31;
  const int qt = 15 - (blk >> 5);
  const int qw = qt * 128 + w * 32;  // wave's first q row

  const __bf16* qp = qb + (size_t)bh * S * D;
  const __bf16* kp = kb + (size_t)bh * S * D;
  const __bf16* vp = vtb + (size_t)bh * D * S;
  char* pw = smem + 65536 + w * 4096;

  // stage precompute (source pre-swizzled; LDS dest wave-uniform + lane*16)
  int ksrc[4], kdst[4], vsrc[4], vdst[4];
#pragma unroll
  for (int j = 0; j < 4; ++j) {
    int c = (w * 4 + j) * 64 + lane;
    int kr = c >> 4, kps = (c & 15) ^ (kr & 7);
    ksrc[j] = kr * D + kps * 8;
    kdst[j] = (w * 4 + j) * 1024;
    int vr = c >> 3, vps = (c & 7) ^ (vr & 7);
    vsrc[j] = vr * S + vps * 8;
    vdst[j] = 16384 + (w * 4 + j) * 1024;
  }

  bf16x8 qf[2][4];
#pragma unroll
  for (int mi = 0; mi < 2; ++mi)
#pragma unroll
    for (int kf = 0; kf < 4; ++kf)
      qf[mi][kf] = *reinterpret_cast<const bf16x8*>(qp + (qw + mi * 16 + ln) * D + kf * 32 + lm * 8);

  f32x4 Oa[2][8] = {};
  float mrow[2][4], lrow[2][4];
#pragma unroll
  for (int mi = 0; mi < 2; ++mi)
#pragma unroll
    for (int r = 0; r < 4; ++r) { mrow[mi][r] = -3.0e38f; lrow[mi][r] = 0.0f; }

  const int ktEnd = 2 * qt + 1;

  // prologue: stage tile 0 into buf 0
#pragma unroll
  for (int j = 0; j < 4; ++j) gll16(kp + ksrc[j], smem + kdst[j]);
#pragma unroll
  for (int j = 0; j < 4; ++j) gll16(vp + vsrc[j], smem + vdst[j]);
  asm volatile("s_waitcnt vmcnt(0)" ::: "memory");
  __builtin_amdgcn_s_barrier();
  __builtin_amdgcn_sched_barrier(0);

  for (int kt = 0; kt <= ktEnd; ++kt) {
    const int kv0 = kt * 64;
    const int cur = kt & 1;

    // issue next-tile stage BEFORE compute (T3 recipe)
    if (kt < ktEnd) {
      const int nk = (kt + 1) * 64;
      char* nbuf = smem + (cur ^ 1) * 32768;
#pragma unroll
      for (int j = 0; j < 4; ++j) gll16(kp + (size_t)nk * D + ksrc[j], nbuf + kdst[j]);
#pragma unroll
      for (int j = 0; j < 4; ++j) gll16(vp + nk + vsrc[j], nbuf + vdst[j] - 16384 + 16384);
    }

    if (kv0 <= qw + 31) {  // wave has unmasked work in this tile
      const char* Kb = smem + cur * 32768;
      const char* Vb = Kb + 16384;
      const bool diag = (kv0 + 63 > qw);

      // S = Q K^T : M=32(q) N=64(kv) K=128(d)
      f32x4 sacc[2][4] = {};
#pragma unroll
      for (int kf = 0; kf < 4; ++kf) {
        bf16x8 kfr[4];
#pragma unroll
        for (int ni = 0; ni < 4; ++ni) {
          int row = ni * 16 + ln;
          int ch = (kf * 4 + lm) ^ (row & 7);
          kfr[ni] = *reinterpret_cast<const bf16x8*>(Kb + row * 256 + ch * 16);
        }
        __builtin_amdgcn_s_setprio(1);
#pragma unroll
        for (int mi = 0; mi < 2; ++mi)
#pragma unroll
          for (int ni = 0; ni < 4; ++ni)
            sacc[mi][ni] = mfma16(qf[mi][kf], kfr[ni], sacc[mi][ni]);
        __builtin_amdgcn_s_setprio(0);
      }

      if (diag) {
#pragma unroll
        for (int ni = 0; ni < 4; ++ni) {
          int c = kv0 + ni * 16 + ln;
#pragma unroll
          for (int mi = 0; mi < 2; ++mi) {
            int q0r = qw + mi * 16 + lm * 4;
#pragma unroll
            for (int r = 0; r < 4; ++r)
              if (c > q0r + r) sacc[mi][ni][r] = -1e30f;
          }
        }
      }

      // online softmax (row = lm*4+r; cols split across 16 lanes)
#pragma unroll
      for (int mi = 0; mi < 2; ++mi)
#pragma unroll
        for (int r = 0; r < 4; ++r) {
          float mx = fmaxf(fmaxf(sacc[mi][0][r], sacc[mi][1][r]),
                           fmaxf(sacc[mi][2][r], sacc[mi][3][r]));
          mx = fmaxf(mx, __shfl_xor(mx, 1, 64));
          mx = fmaxf(mx, __shfl_xor(mx, 2, 64));
          mx = fmaxf(mx, __shfl_xor(mx, 4, 64));
          mx = fmaxf(mx, __shfl_xor(mx, 8, 64));
          float mnew = fmaxf(mrow[mi][r], mx);
          float corr = __expf(mrow[mi][r] - mnew);
          mrow[mi][r] = mnew;
          float rs = 0.0f;
#pragma unroll
          for (int ni = 0; ni < 4; ++ni) {
            float p = __expf(sacc[mi][ni][r] - mnew);
            sacc[mi][ni][r] = p;
            rs += p;
          }
          lrow[mi][r] = lrow[mi][r] * corr + rs;
#pragma unroll
          for (int ni = 0; ni < 8; ++ni) Oa[mi][ni][r] *= corr;
        }

      // P (C-layout) -> per-wave LDS (swizzled) -> A-layout frags
#pragma unroll
      for (int mi = 0; mi < 2; ++mi)
#pragma unroll
        for (int ni = 0; ni < 4; ++ni)
#pragma unroll
          for (int r = 0; r < 4; ++r) {
            int row = mi * 16 + lm * 4 + r;
            int bo = (row * 128 + (ni * 16 + ln) * 2) ^ ((row & 7) << 4);
            *reinterpret_cast<__bf16*>(pw + bo) = (__bf16)sacc[mi][ni][r];
          }

      asm volatile("s_waitcnt lgkmcnt(0)" ::: "memory");
      __builtin_amdgcn_sched_barrier(0);

      // O += P V : M=32(q) N=128(d) K=64(kv)
#pragma unroll
      for (int kf = 0; kf < 2; ++kf) {
        bf16x8 pfr[2], vfr[8];
#pragma unroll
        for (int mi = 0; mi < 2; ++mi) {
          int row = mi * 16 + ln;
          int ch = (kf * 4 + lm) ^ (row & 7);
          pfr[mi] = *reinterpret_cast<const bf16x8*>(pw + row * 128 + ch * 16);
        }
#pragma unroll
        for (int ni = 0; ni < 8; ++ni) {
          int row = ni * 16 + ln;  // d
          int ch = (kf * 4 + lm) ^ (row & 7);
          vfr[ni] = *reinterpret_cast<const bf16x8*>(Vb + row * 128 + ch * 16);
        }
        __builtin_amdgcn_s_setprio(1);
#pragma unroll
        for (int mi = 0; mi < 2; ++mi)
#pragma unroll
          for (int ni = 0; ni < 8; ++ni)
            Oa[mi][ni] = mfma16(pfr[mi], vfr[ni], Oa[mi][ni]);
        __builtin_amdgcn_s_setprio(0);
      }
    }

    // tile boundary: own stages landed + own LDS reads retired, then rendezvous
    asm volatile("s_waitcnt vmcnt(0) lgkmcnt(0)" ::: "memory");
    __builtin_amdgcn_s_barrier();
    __builtin_amdgcn_sched_barrier(0);
  }

  // finish: reduce row sums across 16 lanes, normalize, write merged z
#pragma unroll
  for (int mi = 0; mi < 2; ++mi)
#pragma unroll
    for (int r = 0; r < 4; ++r) {
      float ls = lrow[mi][r];
      ls += __shfl_xor(ls, 1, 64);
      ls += __shfl_xor(ls, 2, 64);
      ls += __shfl_xor(ls, 4, 64);
      ls += __shfl_xor(ls, 8, 64);
      lrow[mi][r] = 1.0f / ls;
    }
  const int b = bh >> 4, h = bh & 15;
#pragma unroll
  for (int mi = 0; mi < 2; ++mi)
#pragma unroll
    for (int ni = 0; ni < 8; ++ni) {
      int d = ni * 16 + ln;
#pragma unroll
      for (int r = 0; r < 4; ++r) {
        int qrow = qw + mi * 16 + lm * 4 + r;
        zb[(size_t)(b * S + qrow) * F + h * D + d] = (__bf16)(Oa[mi][ni][r] * lrow[mi][r]);
      }
    }
}

// ---------------- launch ----------------
extern "C" void kernel_launch(void* const* d_in, const int* in_sizes, int n_in,
                              void* d_out, int out_size, void* d_ws, size_t ws_size,
                              hipStream_t stream) {
  const float* x = (const float*)d_in[0];
  // d_in[1] = causal mask (implemented analytically)
  const float* w_attn = (const float*)d_in[2];
  const float* b_attn = (const float*)d_in[3];
  const float* w_proj = (const float*)d_in[4];
  const float* b_proj = (const float*)d_in[5];
  float* out = (float*)d_out;

  char* ws = (char*)d_ws;
  __bf16* xb    = (__bf16*)(ws + 0);          // 16 MB  [4096][2048] (reused as zb)
  __bf16* wqkv  = (__bf16*)(ws + 16777216);   // 24 MB  [6144][2048] (W^T)
  __bf16* wpro  = (__bf16*)(ws + 41943040);   //  8 MB  [2048][2048] (W^T)
  __bf16* qb    = (__bf16*)(ws + 50331648);   // 16 MB  [bh][s][d]
  __bf16* kb    = (__bf16*)(ws + 67108864);   // 16 MB  [bh][s][d]
  __bf16* vtb   = (__bf16*)(ws + 83886080);   // 16 MB  [bh][d][s]
  __bf16* zb    = xb;  // x fully consumed by QKV GEMM before attention writes z

  (void)hipFuncSetAttribute((const void*)k_gemm_tb<0>,
                            hipFuncAttributeMaxDynamicSharedMemorySize, 147456);
  (void)hipFuncSetAttribute((const void*)k_gemm_tb<1>,
                            hipFuncAttributeMaxDynamicSharedMemorySize, 147456);
  (void)hipFuncSetAttribute((const void*)k_attn,
                            hipFuncAttributeMaxDynamicSharedMemorySize, 81920);

  k_cvt<<<8192, 256, 0, stream>>>(x, xb);
  k_transpose<<<dim3(96, 32), 256, 0, stream>>>(w_attn, wqkv, 2048, 6144);
  k_transpose<<<dim3(32, 32), 256, 0, stream>>>(w_proj, wpro, 2048, 2048);
  // QKV: M=4096 (32 tiles of 128), N=6144 (24 tiles of 256) -> 768 blocks = 3/CU
  k_gemm_tb<0><<<768, 512, 147456, stream>>>(xb, wqkv, b_attn, qb, kb, vtb, nullptr, 24);
  // attention: 512 blocks (LPT + XCD-affinity remap inside)
  k_attn<<<512, 256, 81920, stream>>>(qb, kb, vtb, zb);
  // out-proj: M=4096, N=2048 (8 tiles) -> 256 blocks = 1/CU exact
  k_gemm_tb<1><<<256, 512, 147456, stream>>>(zb, wpro, b_proj, nullptr, nullptr, nullptr, out, 8);
}